// Round 1
// baseline (915.160 us; speedup 1.0000x reference)
//
#include <hip/hip_runtime.h>
#include <cstdint>
#include <cstddef>

#define HID 512
#define BATCH 4096
#define T_STEPS 20

typedef unsigned short ushort_t;
typedef __attribute__((ext_vector_type(8))) __bf16 bf16x8;
typedef __attribute__((ext_vector_type(4))) float f32x4;

typedef __attribute__((address_space(1))) void gvoid;
typedef __attribute__((address_space(3))) void lvoid;

// fp32 -> bf16 round-to-nearest-even (finite inputs only)
__device__ __forceinline__ unsigned short f2bf(float f) {
  unsigned int u = __float_as_uint(f);
  u += 0x7FFFu + ((u >> 16) & 1u);
  return (unsigned short)(u >> 16);
}

__device__ __forceinline__ float wave_max(float v) {
#pragma unroll
  for (int off = 32; off > 0; off >>= 1) v = fmaxf(v, __shfl_xor(v, off));
  return v;
}
__device__ __forceinline__ float wave_sum(float v) {
#pragma unroll
  for (int off = 32; off > 0; off >>= 1) v += __shfl_xor(v, off);
  return v;
}

// async global->LDS, 16B per lane. lds ptr must be wave-uniform (lane*16 is added by HW).
__device__ __forceinline__ void load_lds16(const void* g, void* l) {
  __builtin_amdgcn_global_load_lds((gvoid*)g, (lvoid*)l, 16, 0, 0);
}

// C[M,N] = A[M,K] @ B[N,K]^T ; A,B bf16 row-major (B is "B-transposed" layout, i.e. W[n,k]).
// Tiles: BM x BN, BK=32. 256 threads = 4 waves in 2x2; wave tile (BM/2)x(BN/2);
// 16x16x32 bf16 MFMA. m97-style single-buffer LDS + global_load_lds width 16.
template <int BM, int BN>
__global__ __launch_bounds__(256) void gemm_bt(
    const ushort_t* __restrict__ A, const ushort_t* __restrict__ B,
    float* __restrict__ C, int K, int ldc) {
  constexpr int BK = 32;
  constexpr int WM = BM / 2;
  constexpr int WN = BN / 2;
  constexpr int FM = WM / 16;
  constexpr int FN = WN / 16;
  constexpr int CA = (BM * BK) / (256 * 8);  // 16B chunks per thread for A stage
  constexpr int CB = (BN * BK) / (256 * 8);

  __shared__ ushort_t As[BM * BK];
  __shared__ ushort_t Bs[BN * BK];

  const int tid = threadIdx.x;
  const int wave = tid >> 6;
  const int lane = tid & 63;
  const int quad = lane >> 4;
  const int l16 = lane & 15;

  const int m0 = blockIdx.x * BM;
  const int n0 = blockIdx.y * BN;
  const int wm = (wave & 1) * WM;
  const int wn = (wave >> 1) * WN;

  f32x4 acc[FM][FN] = {};

  const ushort_t* Ag = A + (size_t)m0 * K;
  const ushort_t* Bg = B + (size_t)n0 * K;

  for (int k0 = 0; k0 < K; k0 += BK) {
#pragma unroll
    for (int q = 0; q < CA; ++q) {
      int lb = q * 256 + wave * 64;  // wave-uniform linear chunk base
      int linear = lb + lane;
      int row = linear >> 2;    // 4 lanes per 32-col row (4*16B = 64B)
      int kc = linear & 3;
      load_lds16(Ag + (size_t)row * K + k0 + kc * 8, &As[lb * 8]);
    }
#pragma unroll
    for (int q = 0; q < CB; ++q) {
      int lb = q * 256 + wave * 64;
      int linear = lb + lane;
      int row = linear >> 2;
      int kc = linear & 3;
      load_lds16(Bg + (size_t)row * K + k0 + kc * 8, &Bs[lb * 8]);
    }
    __syncthreads();  // drains vmcnt for the lds loads

    bf16x8 af[FM], bfr[FN];
#pragma unroll
    for (int i = 0; i < FM; ++i)
      af[i] = *(const bf16x8*)&As[(wm + i * 16 + l16) * BK + quad * 8];
#pragma unroll
    for (int j = 0; j < FN; ++j)
      bfr[j] = *(const bf16x8*)&Bs[(wn + j * 16 + l16) * BK + quad * 8];
#pragma unroll
    for (int i = 0; i < FM; ++i)
#pragma unroll
      for (int j = 0; j < FN; ++j)
        acc[i][j] = __builtin_amdgcn_mfma_f32_16x16x32_bf16(af[i], bfr[j], acc[i][j], 0, 0, 0);
    __syncthreads();
  }

  // C/D layout (m89-verified): col = lane&15, row = quad*4 + reg
#pragma unroll
  for (int i = 0; i < FM; ++i)
#pragma unroll
    for (int j = 0; j < FN; ++j) {
      int row = m0 + wm + i * 16 + quad * 4;
      int col = n0 + wn + j * 16 + l16;
#pragma unroll
      for (int r = 0; r < 4; ++r)
        C[(size_t)(row + r) * ldc + col] = acc[i][j][r];
    }
}

// weights fp32 -> bf16; Wcat = [Wi; Wg; Wo] (each 512x512, row-major => flat concat)
__global__ __launch_bounds__(256) void convw_kernel(
    const float* __restrict__ Wi, const float* __restrict__ Wg,
    const float* __restrict__ Wo, const float* __restrict__ Wout,
    ushort_t* __restrict__ Wcat, ushort_t* __restrict__ WoutB) {
  const int nW = HID * HID;  // 262144
  int e = (blockIdx.x * 256 + threadIdx.x) * 4;  // 1024 blocks covers 4*nW
  const float* src;
  ushort_t* dst;
  if (e < nW)            { src = Wi + e;          dst = Wcat + e; }
  else if (e < 2 * nW)   { src = Wg + (e - nW);   dst = Wcat + e; }
  else if (e < 3 * nW)   { src = Wo + (e - 2*nW); dst = Wcat + e; }
  else                   { src = Wout + (e - 3*nW); dst = WoutB + (e - 3*nW); }
  float4 v = *(const float4*)src;
  union { unsigned short us[4]; uint2 u; } p;
  p.us[0] = f2bf(v.x); p.us[1] = f2bf(v.y); p.us[2] = f2bf(v.z); p.us[3] = f2bf(v.w);
  *(uint2*)dst = p.u;
}

// z = y ; zb = bf16(y) ; out[:,0] = softmax(y)·Wfc + bfc   (one wave per row)
__global__ __launch_bounds__(256) void init_kernel(
    const float* __restrict__ y, float* __restrict__ z, ushort_t* __restrict__ zb,
    const float* __restrict__ Wfc, const float* __restrict__ bfc,
    float* __restrict__ out) {
  const int wave = threadIdx.x >> 6;
  const int lane = threadIdx.x & 63;
  const int row = blockIdx.x * 4 + wave;
  const float4* y4 = (const float4*)(y + (size_t)row * HID);
  float4 v0 = y4[lane * 2];
  float4 v1 = y4[lane * 2 + 1];
  float zn[8] = {v0.x, v0.y, v0.z, v0.w, v1.x, v1.y, v1.z, v1.w};
  float4* z4 = (float4*)(z + (size_t)row * HID);
  z4[lane * 2] = v0;
  z4[lane * 2 + 1] = v1;
  union { unsigned short us[8]; uint4 v; } p;
#pragma unroll
  for (int i = 0; i < 8; ++i) p.us[i] = f2bf(zn[i]);
  *(uint4*)(zb + (size_t)row * HID + lane * 8) = p.v;

  const float4* w4 = (const float4*)Wfc;
  float4 w0 = w4[lane * 2], w1 = w4[lane * 2 + 1];
  float w[8] = {w0.x, w0.y, w0.z, w0.w, w1.x, w1.y, w1.z, w1.w};
  float m = zn[0];
#pragma unroll
  for (int i = 1; i < 8; ++i) m = fmaxf(m, zn[i]);
  m = wave_max(m);
  float s = 0.f, d = 0.f;
#pragma unroll
  for (int i = 0; i < 8; ++i) { float e = expf(zn[i] - m); s += e; d += e * w[i]; }
  s = wave_sum(s);
  d = wave_sum(d);
  if (lane == 0) out[(size_t)row * T_STEPS] = d / s + bfc[0];
}

// dh = sigmoid(o) * tanh(sigmoid(i)*tanh(g)) from concat logits C1[b, 0/512/1024 + h]
__global__ __launch_bounds__(256) void act_kernel(
    const float* __restrict__ C1, ushort_t* __restrict__ dh) {
  const int idx = blockIdx.x * 256 + threadIdx.x;  // 4096*128 threads, 4 elems each
  const int b = idx >> 7;
  const int h = (idx & 127) * 4;
  const float* base = C1 + (size_t)b * (3 * HID) + h;
  float4 vi = *(const float4*)(base);
  float4 vg = *(const float4*)(base + HID);
  float4 vo = *(const float4*)(base + 2 * HID);
  float ri[4] = {vi.x, vi.y, vi.z, vi.w};
  float rg[4] = {vg.x, vg.y, vg.z, vg.w};
  float ro[4] = {vo.x, vo.y, vo.z, vo.w};
  union { unsigned short us[4]; uint2 v; } p;
#pragma unroll
  for (int k = 0; k < 4; ++k) {
    float gi = 1.f / (1.f + expf(-ri[k]));
    float gg = tanhf(rg[k]);
    float go = 1.f / (1.f + expf(-ro[k]));
    p.us[k] = f2bf(go * tanhf(gi * gg));
  }
  *(uint2*)(dh + (size_t)b * HID + h) = p.v;
}

// s = softmax(C2[row]+bout); z += dt*s; zb = bf16(z); out[:,t+1] = softmax(z)·Wfc + bfc
__global__ __launch_bounds__(256) void update_kernel(
    const float* __restrict__ C2, const float* __restrict__ bout,
    float* __restrict__ z, ushort_t* __restrict__ zb,
    const float* __restrict__ Wfc, const float* __restrict__ bfc,
    const float* __restrict__ ts, float* __restrict__ out, int t) {
  const int wave = threadIdx.x >> 6;
  const int lane = threadIdx.x & 63;
  const int row = blockIdx.x * 4 + wave;
  const float dt = ts[t + 1] - ts[t];

  const float4* c4 = (const float4*)(C2 + (size_t)row * HID);
  const float4* bo4 = (const float4*)bout;
  float4 a0 = c4[lane * 2], a1 = c4[lane * 2 + 1];
  float4 b0 = bo4[lane * 2], b1 = bo4[lane * 2 + 1];
  float lx[8] = {a0.x + b0.x, a0.y + b0.y, a0.z + b0.z, a0.w + b0.w,
                 a1.x + b1.x, a1.y + b1.y, a1.z + b1.z, a1.w + b1.w};

  float4* z4 = (float4*)(z + (size_t)row * HID);
  float4 zz0 = z4[lane * 2], zz1 = z4[lane * 2 + 1];
  float lz[8] = {zz0.x, zz0.y, zz0.z, zz0.w, zz1.x, zz1.y, zz1.z, zz1.w};

  float m = lx[0];
#pragma unroll
  for (int i = 1; i < 8; ++i) m = fmaxf(m, lx[i]);
  m = wave_max(m);
  float e[8];
  float s = 0.f;
#pragma unroll
  for (int i = 0; i < 8; ++i) { e[i] = expf(lx[i] - m); s += e[i]; }
  s = wave_sum(s);
  const float inv = 1.f / s;

  float zn[8];
#pragma unroll
  for (int i = 0; i < 8; ++i) zn[i] = lz[i] + dt * e[i] * inv;

  z4[lane * 2]     = make_float4(zn[0], zn[1], zn[2], zn[3]);
  z4[lane * 2 + 1] = make_float4(zn[4], zn[5], zn[6], zn[7]);
  union { unsigned short us[8]; uint4 v; } p;
#pragma unroll
  for (int i = 0; i < 8; ++i) p.us[i] = f2bf(zn[i]);
  *(uint4*)(zb + (size_t)row * HID + lane * 8) = p.v;

  const float4* w4 = (const float4*)Wfc;
  float4 w0 = w4[lane * 2], w1 = w4[lane * 2 + 1];
  float w[8] = {w0.x, w0.y, w0.z, w0.w, w1.x, w1.y, w1.z, w1.w};
  float m2 = zn[0];
#pragma unroll
  for (int i = 1; i < 8; ++i) m2 = fmaxf(m2, zn[i]);
  m2 = wave_max(m2);
  float s2 = 0.f, d = 0.f;
#pragma unroll
  for (int i = 0; i < 8; ++i) { float e2 = expf(zn[i] - m2); s2 += e2; d += e2 * w[i]; }
  s2 = wave_sum(s2);
  d = wave_sum(d);
  if (lane == 0) out[(size_t)row * T_STEPS + t + 1] = d / s2 + bfc[0];
}

extern "C" void kernel_launch(void* const* d_in, const int* in_sizes, int n_in,
                              void* d_out, int out_size, void* d_ws, size_t ws_size,
                              hipStream_t stream) {
  const float* y    = (const float*)d_in[0];
  const float* ts   = (const float*)d_in[1];
  const float* Wi   = (const float*)d_in[2];
  // d_in[3] = Wf: computed-but-unused in reference -> skipped
  const float* Wg   = (const float*)d_in[4];
  const float* Wo   = (const float*)d_in[5];
  const float* Wout = (const float*)d_in[6];
  const float* bout = (const float*)d_in[7];
  const float* Wfc  = (const float*)d_in[8];
  const float* bfc  = (const float*)d_in[9];
  float* out = (float*)d_out;

  // workspace layout (bytes), all 256-aligned; total 44,040,192
  char* ws = (char*)d_ws;
  float*    z     = (float*)(ws);                      // 4096*512*4  = 8388608
  ushort_t* zb    = (ushort_t*)(ws + 8388608);         // 4096*512*2  = 4194304
  ushort_t* dh    = (ushort_t*)(ws + 12582912);        // 4096*512*2  = 4194304
  float*    C1    = (float*)(ws + 16777216);           // 4096*1536*4 = 25165824
  float*    C2    = C1;                                // aliased: C1 dead after act
  ushort_t* Wcat  = (ushort_t*)(ws + 41943040);        // 1536*512*2  = 1572864
  ushort_t* WoutB = (ushort_t*)(ws + 43515904);        // 512*512*2   = 524288

  convw_kernel<<<1024, 256, 0, stream>>>(Wi, Wg, Wo, Wout, Wcat, WoutB);
  init_kernel<<<BATCH / 4, 256, 0, stream>>>(y, z, zb, Wfc, bfc, out);

  for (int t = 0; t < T_STEPS - 1; ++t) {
    // logits for i,g,o gates: [4096,1536] = zb @ Wcat^T
    gemm_bt<128, 128><<<dim3(BATCH / 128, 1536 / 128), 256, 0, stream>>>(zb, Wcat, C1, HID, 3 * HID);
    act_kernel<<<(BATCH * HID / 4) / 256, 256, 0, stream>>>(C1, dh);
    // dh @ Wout^T : [4096,512]; 64-row tiles -> 256 blocks (1/CU)
    gemm_bt<64, 128><<<dim3(BATCH / 64, HID / 128), 256, 0, stream>>>(dh, WoutB, C2, HID, HID);
    update_kernel<<<BATCH / 4, 256, 0, stream>>>(C2, bout, z, zb, Wfc, bfc, ts, out, t);
  }
}